// Round 4
// baseline (64.322 us; speedup 1.0000x reference)
//
#include <hip/hip_runtime.h>

// out = w*cumprod(cos(x+pe), axis=-1) + (1-w)*(x+pe)
// x[B=16,S=4096,D=512] f32, pe[1,5000,512] f32, qw scalar. param unused.
//
// Grid remap to kill redundant pe traffic: block = one position s (4096
// blocks), wave = 4 batch rows at that s. pe[s] is loaded once per wave
// into registers (sibling waves hit L1), instead of once per row.
// CU-side vector-memory traffic: 402 MB -> ~300 MB (the R3 bottleneck).
constexpr int D = 512;
constexpr int S = 4096;
constexpr int B = 16;
constexpr int WAVES_PER_BLOCK  = 4;
constexpr int BATCHES_PER_WAVE = B / WAVES_PER_BLOCK;   // 4

// Native clang vector type — works with __builtin_nontemporal_store.
typedef float fx4 __attribute__((ext_vector_type(4)));

// --- DPP multiply-scan (gfx9: row_shr / row_bcast / wave_shr), pure VALU ---
template<int CTRL, int ROW_MASK>
__device__ __forceinline__ float dpp_mul(float x) {
    int t = __builtin_amdgcn_update_dpp(0x3f800000, __float_as_int(x),
                                        CTRL, ROW_MASK, 0xF, false);
    return x * __int_as_float(t);
}
__device__ __forceinline__ float wave_incl_mul_scan(float p) {
    p = dpp_mul<0x111, 0xF>(p);   // row_shr:1
    p = dpp_mul<0x112, 0xF>(p);   // row_shr:2
    p = dpp_mul<0x114, 0xF>(p);   // row_shr:4
    p = dpp_mul<0x118, 0xF>(p);   // row_shr:8
    p = dpp_mul<0x142, 0xA>(p);   // row_bcast:15 -> rows 1,3
    p = dpp_mul<0x143, 0xC>(p);   // row_bcast:31 -> rows 2,3
    return p;
}
__device__ __forceinline__ float wave_shr1_id(float p) {
    int t = __builtin_amdgcn_update_dpp(0x3f800000, __float_as_int(p),
                                        0x138 /*wave_shr:1*/, 0xF, 0xF, false);
    return __int_as_float(t);
}

__global__ __launch_bounds__(256) void qpe_kernel(
    const fx4* __restrict__ x4, const fx4* __restrict__ pe4,
    const float* __restrict__ qw, fx4* __restrict__ out4)
{
    const int lane = threadIdx.x & 63;
    const int wid  = threadIdx.x >> 6;
    const int s    = blockIdx.x;                    // sequence position
    const int b0   = wid * BATCHES_PER_WAVE;        // first batch for this wave

    const float w   = 1.0f / (1.0f + __expf(-qw[0]));
    const float omw = 1.0f - w;

    const size_t lane2 = (size_t)lane * 2;

    // pe[s]: one 32 B/lane read, shared across the wave's 4 batch rows.
    const size_t pb = (size_t)s * (D / 4) + lane2;
    const fx4 pv0 = pe4[pb], pv1 = pe4[pb + 1];

    // Issue all x loads up front (4 rows x 2 fx4).
    size_t xb[BATCHES_PER_WAVE];
    fx4 xv[BATCHES_PER_WAVE][2];
    #pragma unroll
    for (int r = 0; r < BATCHES_PER_WAVE; ++r) {
        const size_t row = (size_t)(b0 + r) * S + s;
        xb[r] = row * (D / 4) + lane2;
        xv[r][0] = x4[xb[r]];
        xv[r][1] = x4[xb[r] + 1];
    }

    float o[BATCHES_PER_WAVE][8], c[BATCHES_PER_WAVE][8], p[BATCHES_PER_WAVE];
    #pragma unroll
    for (int r = 0; r < BATCHES_PER_WAVE; ++r) {
        #pragma unroll
        for (int j = 0; j < 4; ++j) {
            o[r][j]     = xv[r][0][j] + pv0[j];
            o[r][4 + j] = xv[r][1][j] + pv1[j];
        }
        #pragma unroll
        for (int j = 0; j < 8; ++j) c[r][j] = __cosf(o[r][j]);
        float q = c[r][0];
        #pragma unroll
        for (int j = 1; j < 8; ++j) q *= c[r][j];
        p[r] = q;
    }

    // Four independent DPP scans — interleaved by the scheduler (pure VALU).
    #pragma unroll
    for (int r = 0; r < BATCHES_PER_WAVE; ++r) {
        p[r] = wave_incl_mul_scan(p[r]);
        p[r] = wave_shr1_id(p[r]);                  // exclusive prefix, lane0=1
    }

    #pragma unroll
    for (int r = 0; r < BATCHES_PER_WAVE; ++r) {
        float run = p[r];
        float res[8];
        #pragma unroll
        for (int j = 0; j < 8; ++j) {
            run *= c[r][j];
            res[j] = w * run + omw * o[r][j];
        }
        fx4 s0 = { res[0], res[1], res[2], res[3] };
        fx4 s1 = { res[4], res[5], res[6], res[7] };
        // Non-temporal: keep the 134 MB output stream out of L3 so x stays.
        __builtin_nontemporal_store(s0, &out4[xb[r]]);
        __builtin_nontemporal_store(s1, &out4[xb[r] + 1]);
    }
}

extern "C" void kernel_launch(void* const* d_in, const int* in_sizes, int n_in,
                              void* d_out, int out_size, void* d_ws, size_t ws_size,
                              hipStream_t stream) {
    const fx4* x  = (const fx4*)d_in[0];
    const fx4* pe = (const fx4*)d_in[1];
    // d_in[2] = param (unused by the closed form)
    const float* qw  = (const float*)d_in[3];
    fx4* out = (fx4*)d_out;

    qpe_kernel<<<S, WAVES_PER_BLOCK * 64, 0, stream>>>(x, pe, qw, out);
}

// Round 5
// 55.778 us; speedup vs baseline: 1.1532x; 1.1532x over previous
//
#include <hip/hip_runtime.h>

// out = w*cumprod(cos(x+pe), axis=-1) + (1-w)*(x+pe)
// x[B=16,S=4096,D=512] f32, qw scalar. pe is COMPUTED on the fly:
//   pe[s, 2k]   = sin(s * div_k),  pe[s, 2k+1] = cos(s * div_k),
//   div_k = 10000^(-k/256),  k = lane*4 + j  (each lane owns 4 pairs).
// This removes 134 MB of pe vector-path traffic; R3 showed the kernel is
// pinned at the ~7.3 TB/s CU-side vector-memory ceiling, so bytes are the
// only lever. Layout stays R3's linear streaming (the R4 batch-major remap
// with 8 MiB power-of-2 strides regressed).
constexpr int D = 512;
constexpr int S = 4096;
constexpr int B = 16;
constexpr int ROWS = B * S;            // 65536
constexpr int WAVES_PER_BLOCK = 4;     // 256-thread blocks
constexpr int ROWS_PER_WAVE  = 2;      // two independent scan chains (ILP)

typedef float fx4 __attribute__((ext_vector_type(4)));

// --- DPP multiply-scan (gfx9: row_shr / row_bcast / wave_shr), pure VALU ---
template<int CTRL, int ROW_MASK>
__device__ __forceinline__ float dpp_mul(float x) {
    int t = __builtin_amdgcn_update_dpp(0x3f800000, __float_as_int(x),
                                        CTRL, ROW_MASK, 0xF, false);
    return x * __int_as_float(t);
}
__device__ __forceinline__ float wave_incl_mul_scan(float p) {
    p = dpp_mul<0x111, 0xF>(p);   // row_shr:1
    p = dpp_mul<0x112, 0xF>(p);   // row_shr:2
    p = dpp_mul<0x114, 0xF>(p);   // row_shr:4
    p = dpp_mul<0x118, 0xF>(p);   // row_shr:8
    p = dpp_mul<0x142, 0xA>(p);   // row_bcast:15 -> rows 1,3
    p = dpp_mul<0x143, 0xC>(p);   // row_bcast:31 -> rows 2,3
    return p;
}
__device__ __forceinline__ float wave_shr1_id(float p) {
    int t = __builtin_amdgcn_update_dpp(0x3f800000, __float_as_int(p),
                                        0x138 /*wave_shr:1*/, 0xF, 0xF, false);
    return __int_as_float(t);
}

__global__ __launch_bounds__(256) void qpe_kernel(
    const fx4* __restrict__ x4, const float* __restrict__ qw,
    fx4* __restrict__ out4)
{
    const int lane = threadIdx.x & 63;
    const int wid  = threadIdx.x >> 6;
    const int wave = blockIdx.x * WAVES_PER_BLOCK + wid;
    const int row0 = wave * ROWS_PER_WAVE;

    const float w   = 1.0f / (1.0f + __expf(-qw[0]));
    const float omw = 1.0f - w;

    // Per-lane frequencies: div_j = 10000^(-(lane*4+j)/256) = exp2(k * c).
    const float NEG_LOG2_10K_OVER_256 = -0.05190512648261503f; // -log2(1e4)/256
    float div[4];
    #pragma unroll
    for (int j = 0; j < 4; ++j)
        div[j] = exp2f((float)(lane * 4 + j) * NEG_LOG2_10K_OVER_256);

    // Issue x loads up front (2 rows x 2 fx4, linear streaming).
    size_t xb[ROWS_PER_WAVE];
    fx4 xv[ROWS_PER_WAVE][2];
    #pragma unroll
    for (int r = 0; r < ROWS_PER_WAVE; ++r) {
        xb[r] = (size_t)(row0 + r) * (D / 4) + (size_t)lane * 2;
        xv[r][0] = x4[xb[r]];
        xv[r][1] = x4[xb[r] + 1];
    }

    float o[ROWS_PER_WAVE][8], c[ROWS_PER_WAVE][8], p[ROWS_PER_WAVE];
    #pragma unroll
    for (int r = 0; r < ROWS_PER_WAVE; ++r) {
        const float sf = (float)((row0 + r) & (S - 1));   // position s
        float xr[8] = { xv[r][0][0], xv[r][0][1], xv[r][0][2], xv[r][0][3],
                        xv[r][1][0], xv[r][1][1], xv[r][1][2], xv[r][1][3] };
        #pragma unroll
        for (int j = 0; j < 4; ++j) {
            const float a = sf * div[j];
            o[r][2 * j]     = xr[2 * j]     + __sinf(a);
            o[r][2 * j + 1] = xr[2 * j + 1] + __cosf(a);
        }
        #pragma unroll
        for (int j = 0; j < 8; ++j) c[r][j] = __cosf(o[r][j]);
        float q = c[r][0];
        #pragma unroll
        for (int j = 1; j < 8; ++j) q *= c[r][j];
        p[r] = q;
    }

    // Two independent DPP scans (pure VALU, no LDS pipe).
    #pragma unroll
    for (int r = 0; r < ROWS_PER_WAVE; ++r) {
        p[r] = wave_incl_mul_scan(p[r]);
        p[r] = wave_shr1_id(p[r]);                 // exclusive prefix, lane0=1
    }

    #pragma unroll
    for (int r = 0; r < ROWS_PER_WAVE; ++r) {
        float run = p[r];
        float res[8];
        #pragma unroll
        for (int j = 0; j < 8; ++j) {
            run *= c[r][j];
            res[j] = w * run + omw * o[r][j];
        }
        fx4 s0 = { res[0], res[1], res[2], res[3] };
        fx4 s1 = { res[4], res[5], res[6], res[7] };
        // Non-temporal: keep the output stream from evicting x in L3.
        __builtin_nontemporal_store(s0, &out4[xb[r]]);
        __builtin_nontemporal_store(s1, &out4[xb[r] + 1]);
    }
}

extern "C" void kernel_launch(void* const* d_in, const int* in_sizes, int n_in,
                              void* d_out, int out_size, void* d_ws, size_t ws_size,
                              hipStream_t stream) {
    const fx4* x  = (const fx4*)d_in[0];
    // d_in[1] = pe (recomputed on device), d_in[2] = param (unused)
    const float* qw  = (const float*)d_in[3];
    fx4* out = (fx4*)d_out;

    const int blocks = ROWS / (WAVES_PER_BLOCK * ROWS_PER_WAVE); // 8192
    qpe_kernel<<<blocks, WAVES_PER_BLOCK * 64, 0, stream>>>(x, qw, out);
}

// Round 6
// 44.829 us; speedup vs baseline: 1.4348x; 1.2442x over previous
//
#include <hip/hip_runtime.h>

// out = w*cumprod(cos(x+pe), axis=-1) + (1-w)*(x+pe)
// x[B=16,S=4096,D=512] f32, qw scalar. pe computed on the fly:
//   pe[s,2k]=sin(s*div_k), pe[s,2k+1]=cos(s*div_k), div_k=10000^(-k/256),
//   k = lane*4+j (each lane owns 4 sin/cos pairs of its 8 elements).
//
// R5 lesson: kernel is HBM mixed-r/w bound (~4 TB/s achieved vs 6.3 copy
// ceiling). Levers: (1) plain stores — __builtin_nontemporal_store inflated
// WRITE_SIZE 134->162 MB; (2) more loads in flight per wave (4 rows) to
// approach copy-kernel MLP; (3) per-row store-as-ready to overlap writes
// with remaining compute. Layout stays fully linear (R4 strided remap hurt).
constexpr int D = 512;
constexpr int S = 4096;
constexpr int B = 16;
constexpr int ROWS = B * S;            // 65536
constexpr int WAVES_PER_BLOCK = 4;     // 256-thread blocks
constexpr int ROWS_PER_WAVE  = 4;      // 4 independent scan chains, 8 loads in flight

typedef float fx4 __attribute__((ext_vector_type(4)));

// --- DPP multiply-scan (gfx9: row_shr / row_bcast / wave_shr), pure VALU ---
template<int CTRL, int ROW_MASK>
__device__ __forceinline__ float dpp_mul(float x) {
    int t = __builtin_amdgcn_update_dpp(0x3f800000, __float_as_int(x),
                                        CTRL, ROW_MASK, 0xF, false);
    return x * __int_as_float(t);
}
__device__ __forceinline__ float wave_incl_mul_scan(float p) {
    p = dpp_mul<0x111, 0xF>(p);   // row_shr:1
    p = dpp_mul<0x112, 0xF>(p);   // row_shr:2
    p = dpp_mul<0x114, 0xF>(p);   // row_shr:4
    p = dpp_mul<0x118, 0xF>(p);   // row_shr:8
    p = dpp_mul<0x142, 0xA>(p);   // row_bcast:15 -> rows 1,3
    p = dpp_mul<0x143, 0xC>(p);   // row_bcast:31 -> rows 2,3
    return p;
}
__device__ __forceinline__ float wave_shr1_id(float p) {
    int t = __builtin_amdgcn_update_dpp(0x3f800000, __float_as_int(p),
                                        0x138 /*wave_shr:1*/, 0xF, 0xF, false);
    return __int_as_float(t);
}

__global__ __launch_bounds__(256) void qpe_kernel(
    const fx4* __restrict__ x4, const float* __restrict__ qw,
    fx4* __restrict__ out4)
{
    const int lane = threadIdx.x & 63;
    const int wid  = threadIdx.x >> 6;
    const int wave = blockIdx.x * WAVES_PER_BLOCK + wid;
    const int row0 = wave * ROWS_PER_WAVE;

    const float w   = 1.0f / (1.0f + __expf(-qw[0]));
    const float omw = 1.0f - w;

    // Per-lane frequencies: div_j = 10000^(-(lane*4+j)/256) = exp2(k * c).
    const float NEG_LOG2_10K_OVER_256 = -0.05190512648261503f; // -log2(1e4)/256
    float div[4];
    #pragma unroll
    for (int j = 0; j < 4; ++j)
        div[j] = exp2f((float)(lane * 4 + j) * NEG_LOG2_10K_OVER_256);

    // Issue ALL x loads up front (4 rows x 2 fx4 = 8 independent 16B loads).
    size_t xb[ROWS_PER_WAVE];
    fx4 xv[ROWS_PER_WAVE][2];
    #pragma unroll
    for (int r = 0; r < ROWS_PER_WAVE; ++r) {
        xb[r] = (size_t)(row0 + r) * (D / 4) + (size_t)lane * 2;
        xv[r][0] = x4[xb[r]];
        xv[r][1] = x4[xb[r] + 1];
    }

    // Per row: pe + add + cos + local product + DPP scan + blend + store.
    // Rows are independent; storing each as soon as it's done overlaps the
    // write stream with the remaining rows' ALU work.
    #pragma unroll
    for (int r = 0; r < ROWS_PER_WAVE; ++r) {
        const float sf = (float)((row0 + r) & (S - 1));   // position s
        float o[8], c[8];
        #pragma unroll
        for (int j = 0; j < 4; ++j) {
            const float a = sf * div[j];
            o[2 * j]     = xv[r][0][0] * 0.0f + 0.0f; // placeholder overwritten below
            o[2 * j + 1] = 0.0f;
        }
        {
            float xr[8] = { xv[r][0][0], xv[r][0][1], xv[r][0][2], xv[r][0][3],
                            xv[r][1][0], xv[r][1][1], xv[r][1][2], xv[r][1][3] };
            #pragma unroll
            for (int j = 0; j < 4; ++j) {
                const float a = sf * div[j];
                o[2 * j]     = xr[2 * j]     + __sinf(a);
                o[2 * j + 1] = xr[2 * j + 1] + __cosf(a);
            }
        }
        #pragma unroll
        for (int j = 0; j < 8; ++j) c[j] = __cosf(o[j]);

        float p = c[0];
        #pragma unroll
        for (int j = 1; j < 8; ++j) p *= c[j];

        p = wave_incl_mul_scan(p);
        p = wave_shr1_id(p);                       // exclusive prefix, lane0=1

        float run = p, res[8];
        #pragma unroll
        for (int j = 0; j < 8; ++j) {
            run *= c[j];
            res[j] = w * run + omw * o[j];
        }
        out4[xb[r]]     = (fx4){ res[0], res[1], res[2], res[3] };
        out4[xb[r] + 1] = (fx4){ res[4], res[5], res[6], res[7] };
    }
}

extern "C" void kernel_launch(void* const* d_in, const int* in_sizes, int n_in,
                              void* d_out, int out_size, void* d_ws, size_t ws_size,
                              hipStream_t stream) {
    const fx4* x  = (const fx4*)d_in[0];
    // d_in[1] = pe (recomputed on device), d_in[2] = param (unused)
    const float* qw  = (const float*)d_in[3];
    fx4* out = (fx4*)d_out;

    const int blocks = ROWS / (WAVES_PER_BLOCK * ROWS_PER_WAVE); // 4096
    qpe_kernel<<<blocks, WAVES_PER_BLOCK * 64, 0, stream>>>(x, qw, out);
}